// Round 4
// baseline (51.843 us; speedup 1.0000x reference)
//
#include <hip/hip_runtime.h>
#include <hip/hip_bf16.h>
#include <math.h>

// Problem constants (fixed by setup_inputs): B=8, M=256, D=768, K=100
#define NROWS 2048
#define DDIM  768
#define KNEG  100
#define NLOGITS 101
#define MT 7            // ceil(101/16) M-tiles -> 112 padded logits
#define KT 24           // 768 / 32 K-steps

typedef __attribute__((ext_vector_type(8))) short short8;   // 8 bf16 = one MFMA frag
typedef __attribute__((ext_vector_type(4))) float floatx4;  // MFMA accumulator

static constexpr float TEMP_INV = 10.0f;   // 1 / 0.1
static constexpr float EPS_NORM = 1e-8f;

__device__ __forceinline__ unsigned pack_bf2(float a, float b) {
    __hip_bfloat16 ha = __float2bfloat16(a), hb = __float2bfloat16(b);
    unsigned short sa, sb;
    __builtin_memcpy(&sa, &ha, 2);
    __builtin_memcpy(&sb, &hb, 2);
    return (unsigned)sa | ((unsigned)sb << 16);
}

// Kernel 1: normalize target rows -> bf16 (3 MB total; L2-resident gather src).
// One wave per row, 4 rows per block.
__global__ __launch_bounds__(256) void cl_prep_kernel(
        const float* __restrict__ targets,
        __hip_bfloat16* __restrict__ tn) {
    const int wave = threadIdx.x >> 6, lane = threadIdx.x & 63;
    const int row = blockIdx.x * 4 + wave;
    const float4* tv = (const float4*)(targets + (size_t)row * DDIM);
    const float4 a0 = tv[2 * lane], a1 = tv[2 * lane + 1], b0 = tv[128 + lane];

    float ss = 0.f;
    ss = fmaf(a0.x, a0.x, ss); ss = fmaf(a0.y, a0.y, ss);
    ss = fmaf(a0.z, a0.z, ss); ss = fmaf(a0.w, a0.w, ss);
    ss = fmaf(a1.x, a1.x, ss); ss = fmaf(a1.y, a1.y, ss);
    ss = fmaf(a1.z, a1.z, ss); ss = fmaf(a1.w, a1.w, ss);
    ss = fmaf(b0.x, b0.x, ss); ss = fmaf(b0.y, b0.y, ss);
    ss = fmaf(b0.z, b0.z, ss); ss = fmaf(b0.w, b0.w, ss);
    #pragma unroll
    for (int off = 32; off > 0; off >>= 1) ss += __shfl_xor(ss, off);
    const float it = 1.0f / fmaxf(sqrtf(ss), EPS_NORM);

    uint4 ua;
    ua.x = pack_bf2(a0.x * it, a0.y * it);
    ua.y = pack_bf2(a0.z * it, a0.w * it);
    ua.z = pack_bf2(a1.x * it, a1.y * it);
    ua.w = pack_bf2(a1.z * it, a1.w * it);
    uint2 ub;
    ub.x = pack_bf2(b0.x * it, b0.y * it);
    ub.y = pack_bf2(b0.z * it, b0.w * it);

    __hip_bfloat16* trow = tn + (size_t)row * DDIM;
    ((uint4*)trow)[lane] = ua;          // dims [8*lane, 8*lane+8)
    ((uint2*)(trow + 512))[lane] = ub;  // dims [512+4*lane, +4)
}

// Kernel 2: one wave per pred row (4 rows / 256-thread block).
// MFMA matvec: A = 16 gathered target rows x 32 dims, B = pred broadcast to
// all 16 cols. No per-dot cross-lane reduction; dots accumulate in AGPRs.
__global__ __launch_bounds__(256) void cl_rowloss_kernel(
        const float* __restrict__ preds,
        const __hip_bfloat16* __restrict__ tn,
        const int* __restrict__ neg_idx,
        float* __restrict__ row_loss) {
    const int wave = threadIdx.x >> 6, lane = threadIdx.x & 63;
    const int i = blockIdx.x * 4 + wave;

    __shared__ __align__(16) unsigned short pn[4][DDIM];   // normalized pred, bf16
    __shared__ __align__(16) float logits[4][MT * 16];

    // --- load pred row, normalize, pack bf16 -> LDS (wave-local) ---
    const float4* pv = (const float4*)(preds + (size_t)i * DDIM);
    const float4 a0 = pv[2 * lane], a1 = pv[2 * lane + 1], b0 = pv[128 + lane];
    float ss = 0.f;
    ss = fmaf(a0.x, a0.x, ss); ss = fmaf(a0.y, a0.y, ss);
    ss = fmaf(a0.z, a0.z, ss); ss = fmaf(a0.w, a0.w, ss);
    ss = fmaf(a1.x, a1.x, ss); ss = fmaf(a1.y, a1.y, ss);
    ss = fmaf(a1.z, a1.z, ss); ss = fmaf(a1.w, a1.w, ss);
    ss = fmaf(b0.x, b0.x, ss); ss = fmaf(b0.y, b0.y, ss);
    ss = fmaf(b0.z, b0.z, ss); ss = fmaf(b0.w, b0.w, ss);
    #pragma unroll
    for (int off = 32; off > 0; off >>= 1) ss += __shfl_xor(ss, off);
    const float inv = 1.0f / fmaxf(sqrtf(ss), EPS_NORM);

    uint4 ua;
    ua.x = pack_bf2(a0.x * inv, a0.y * inv);
    ua.y = pack_bf2(a0.z * inv, a0.w * inv);
    ua.z = pack_bf2(a1.x * inv, a1.y * inv);
    ua.w = pack_bf2(a1.z * inv, a1.w * inv);
    uint2 ub;
    ub.x = pack_bf2(b0.x * inv, b0.y * inv);
    ub.y = pack_bf2(b0.z * inv, b0.w * inv);

    unsigned short* prow = pn[wave];
    ((uint4*)prow)[lane] = ua;
    ((uint2*)(prow + 512))[lane] = ub;

    // --- gather row indices: lane j holds index for logit j (and j+64) ---
    int idxA = i, idxB = i;
    if (lane >= 1)  idxA = neg_idx[(size_t)i * KNEG + lane - 1];   // j = lane in [1,63]
    if (lane <= 36) idxB = neg_idx[(size_t)i * KNEG + 63 + lane];  // j = 64+lane in [64,100]

    // --- per-M-tile A base pointers: lane reads row r[tile*16 + (lane&15)] ---
    const short8* base[MT];
    #pragma unroll
    for (int t = 0; t < MT; ++t) {
        const int src = (t * 16 + (lane & 15)) & 63;
        const int r = __shfl((t < 4) ? idxA : idxB, src);
        base[t] = (const short8*)(tn + (size_t)r * DDIM) + (lane >> 4);
    }
    const short8* bsrc = (const short8*)prow + (lane >> 4);

    // --- MFMA matvec: 24 K-steps x 7 M-tiles, fully unrolled (imm offsets) ---
    floatx4 acc[MT] = {};
    #pragma unroll
    for (int k = 0; k < KT; ++k) {
        const short8 bf = bsrc[4 * k];   // pred frag (same for all cols)
        #pragma unroll
        for (int t = 0; t < MT; ++t)
            acc[t] = __builtin_amdgcn_mfma_f32_16x16x32_bf16(base[t][4 * k], bf,
                                                             acc[t], 0, 0, 0);
    }

    // --- extract dots: C/D map col=lane&15, row=(lane>>4)*4+reg [m89] ---
    float* lrow = logits[wave];
    if ((lane & 15) == 0) {
        const int rb = (lane >> 4) * 4;
        #pragma unroll
        for (int t = 0; t < MT; ++t) {
            floatx4 v = acc[t] * TEMP_INV;
            *(floatx4*)(lrow + t * 16 + rb) = v;
        }
    }

    // --- wave-local logsumexp over logits[0..100]; loss = lse - logits[0] ---
    const float v0 = lrow[lane];
    const float v1 = (lane <= NLOGITS - 65) ? lrow[64 + lane] : -INFINITY;
    float m = fmaxf(v0, v1);
    #pragma unroll
    for (int off = 32; off > 0; off >>= 1) m = fmaxf(m, __shfl_xor(m, off));
    float e = expf(v0 - m);
    if (lane <= NLOGITS - 65) e += expf(v1 - m);
    #pragma unroll
    for (int off = 32; off > 0; off >>= 1) e += __shfl_xor(e, off);
    if (lane == 0) row_loss[i] = (m + logf(e)) - lrow[0];
}

// Kernel 3: deterministic final mean over the 2048 row losses.
__global__ void cl_reduce_kernel(const float* __restrict__ row_loss,
                                 float* __restrict__ out) {
    const int tid = threadIdx.x; // 256
    float s = 0.f;
    for (int i = tid; i < NROWS; i += 256) s += row_loss[i];
    #pragma unroll
    for (int off = 32; off > 0; off >>= 1) s += __shfl_down(s, off);
    __shared__ float sw[4];
    const int wave = tid >> 6, lane = tid & 63;
    if (lane == 0) sw[wave] = s;
    __syncthreads();
    if (tid == 0) out[0] = (sw[0] + sw[1] + sw[2] + sw[3]) / (float)NROWS;
}

extern "C" void kernel_launch(void* const* d_in, const int* in_sizes, int n_in,
                              void* d_out, int out_size, void* d_ws, size_t ws_size,
                              hipStream_t stream) {
    const float* preds   = (const float*)d_in[0];
    const float* targets = (const float*)d_in[1];
    const int*   neg_idx = (const int*)d_in[2];
    float* out = (float*)d_out;

    // workspace: tn_bf16 (3 MB, aligned at base) | row_loss[N]
    __hip_bfloat16* tn = (__hip_bfloat16*)d_ws;
    float* row_loss = (float*)((char*)d_ws + (size_t)NROWS * DDIM * sizeof(__hip_bfloat16));

    cl_prep_kernel<<<NROWS / 4, 256, 0, stream>>>(targets, tn);
    cl_rowloss_kernel<<<NROWS / 4, 256, 0, stream>>>(preds, tn, neg_idx, row_loss);
    cl_reduce_kernel<<<1, 256, 0, stream>>>(row_loss, out);
}

// Round 5
// 51.142 us; speedup vs baseline: 1.0137x; 1.0137x over previous
//
#include <hip/hip_runtime.h>
#include <hip/hip_bf16.h>
#include <math.h>

// Problem constants (fixed by setup_inputs): B=8, M=256, D=768, K=100
#define NROWS 2048
#define DDIM  768
#define KNEG  100
#define NLOGITS 101
#define MT 7            // ceil(101/16) M-tiles -> 112 padded logits
#define KT 24           // 768 / 32 K-steps

typedef __attribute__((ext_vector_type(8))) short short8;   // 8 bf16 = one MFMA frag
typedef __attribute__((ext_vector_type(4))) float floatx4;  // MFMA accumulator

static constexpr float TEMP_INV = 10.0f;   // 1 / 0.1
static constexpr float EPS_NORM = 1e-8f;

__device__ __forceinline__ unsigned pack_bf2(float a, float b) {
    __hip_bfloat16 ha = __float2bfloat16(a), hb = __float2bfloat16(b);
    unsigned short sa, sb;
    __builtin_memcpy(&sa, &ha, 2);
    __builtin_memcpy(&sb, &hb, 2);
    return (unsigned)sa | ((unsigned)sb << 16);
}

// Kernel 1: normalize target rows -> bf16 (3 MB total; L2-resident gather src).
__global__ __launch_bounds__(256) void cl_prep_kernel(
        const float* __restrict__ targets,
        __hip_bfloat16* __restrict__ tn) {
    const int wave = threadIdx.x >> 6, lane = threadIdx.x & 63;
    const int row = blockIdx.x * 4 + wave;
    const float4* tv = (const float4*)(targets + (size_t)row * DDIM);
    const float4 a0 = tv[2 * lane], a1 = tv[2 * lane + 1], b0 = tv[128 + lane];

    float ss = 0.f;
    ss = fmaf(a0.x, a0.x, ss); ss = fmaf(a0.y, a0.y, ss);
    ss = fmaf(a0.z, a0.z, ss); ss = fmaf(a0.w, a0.w, ss);
    ss = fmaf(a1.x, a1.x, ss); ss = fmaf(a1.y, a1.y, ss);
    ss = fmaf(a1.z, a1.z, ss); ss = fmaf(a1.w, a1.w, ss);
    ss = fmaf(b0.x, b0.x, ss); ss = fmaf(b0.y, b0.y, ss);
    ss = fmaf(b0.z, b0.z, ss); ss = fmaf(b0.w, b0.w, ss);
    #pragma unroll
    for (int off = 32; off > 0; off >>= 1) ss += __shfl_xor(ss, off);
    const float it = 1.0f / fmaxf(sqrtf(ss), EPS_NORM);

    uint4 ua;
    ua.x = pack_bf2(a0.x * it, a0.y * it);
    ua.y = pack_bf2(a0.z * it, a0.w * it);
    ua.z = pack_bf2(a1.x * it, a1.y * it);
    ua.w = pack_bf2(a1.z * it, a1.w * it);
    uint2 ub;
    ub.x = pack_bf2(b0.x * it, b0.y * it);
    ub.y = pack_bf2(b0.z * it, b0.w * it);

    __hip_bfloat16* trow = tn + (size_t)row * DDIM;
    ((uint4*)trow)[lane] = ua;          // dims [8*lane, 8*lane+8)
    ((uint2*)(trow + 512))[lane] = ub;  // dims [512+4*lane, +4)
}

// Depth-3 software-pipelined MFMA chain over the K dimension.
// All indices static after full unroll -> registers, deep vmcnt overlap.
template<int NT>
__device__ __forceinline__ void mfma_chain(const short8* const* base,
                                           const short8* bsrc,
                                           floatx4* acc) {
    short8 A[3][4];
    short8 Bv[3];
    #pragma unroll
    for (int kk = 0; kk < 3; ++kk) {
        #pragma unroll
        for (int t = 0; t < NT; ++t) A[kk][t] = base[t][4 * kk];
        Bv[kk] = bsrc[4 * kk];
    }
    #pragma unroll
    for (int k = 0; k < KT; ++k) {
        const int cur = k % 3;
        #pragma unroll
        for (int t = 0; t < NT; ++t)
            acc[t] = __builtin_amdgcn_mfma_f32_16x16x32_bf16(A[cur][t], Bv[cur],
                                                             acc[t], 0, 0, 0);
        if (k + 3 < KT) {
            #pragma unroll
            for (int t = 0; t < NT; ++t) A[cur][t] = base[t][4 * (k + 3)];
            Bv[cur] = bsrc[4 * (k + 3)];
        }
    }
}

// Kernel 2: 2 waves per pred row (tiles 0-3 / 4-6), 2 rows per 256-thread
// block, grid=1024 -> 16 waves/CU. MFMA matvec, dots accumulate in AGPRs.
__global__ __launch_bounds__(256, 4) void cl_rowloss_kernel(
        const float* __restrict__ preds,
        const __hip_bfloat16* __restrict__ tn,
        const int* __restrict__ neg_idx,
        float* __restrict__ row_loss) {
    const int wave = threadIdx.x >> 6, lane = threadIdx.x & 63;
    const int rp = wave >> 1;      // row slot in block (0/1)
    const int half = wave & 1;     // tile half (0: tiles 0-3, 1: tiles 4-6)
    const int i = blockIdx.x * 2 + rp;

    __shared__ __align__(16) unsigned short pn[2][DDIM];   // normalized pred bf16
    __shared__ __align__(16) float logits[2][MT * 16];

    // --- this wave's gather indices (one logit per lane) ---
    int idx;
    if (half == 0) {
        idx = (lane == 0) ? i : neg_idx[(size_t)i * KNEG + lane - 1];   // j = lane
    } else {
        const int t = (lane <= 36) ? lane : 36;                         // j = 64+t
        idx = neg_idx[(size_t)i * KNEG + 63 + t];
    }

    // --- per-tile A base pointers: lane reads row r[tile*16+(lane&15)] ---
    const short8* base[4];
    #pragma unroll
    for (int t = 0; t < 4; ++t) {
        const int src = (t * 16 + (lane & 15)) & 63;
        const int r = __shfl(idx, src);
        base[t] = (const short8*)(tn + (size_t)r * DDIM) + (lane >> 4);
    }

    // --- half 0 loads/normalizes pred row -> LDS bf16 ---
    if (half == 0) {
        const float4* pv = (const float4*)(preds + (size_t)i * DDIM);
        const float4 a0 = pv[2 * lane], a1 = pv[2 * lane + 1], b0 = pv[128 + lane];
        float ss = 0.f;
        ss = fmaf(a0.x, a0.x, ss); ss = fmaf(a0.y, a0.y, ss);
        ss = fmaf(a0.z, a0.z, ss); ss = fmaf(a0.w, a0.w, ss);
        ss = fmaf(a1.x, a1.x, ss); ss = fmaf(a1.y, a1.y, ss);
        ss = fmaf(a1.z, a1.z, ss); ss = fmaf(a1.w, a1.w, ss);
        ss = fmaf(b0.x, b0.x, ss); ss = fmaf(b0.y, b0.y, ss);
        ss = fmaf(b0.z, b0.z, ss); ss = fmaf(b0.w, b0.w, ss);
        #pragma unroll
        for (int off = 32; off > 0; off >>= 1) ss += __shfl_xor(ss, off);
        const float inv = 1.0f / fmaxf(sqrtf(ss), EPS_NORM);
        uint4 ua;
        ua.x = pack_bf2(a0.x * inv, a0.y * inv);
        ua.y = pack_bf2(a0.z * inv, a0.w * inv);
        ua.z = pack_bf2(a1.x * inv, a1.y * inv);
        ua.w = pack_bf2(a1.z * inv, a1.w * inv);
        uint2 ub;
        ub.x = pack_bf2(b0.x * inv, b0.y * inv);
        ub.y = pack_bf2(b0.z * inv, b0.w * inv);
        unsigned short* prow = pn[rp];
        ((uint4*)prow)[lane] = ua;
        ((uint2*)(prow + 512))[lane] = ub;
    }
    __syncthreads();

    // --- MFMA matvec over K, depth-3 pipelined ---
    const short8* bsrc = (const short8*)(pn[rp]) + (lane >> 4);
    floatx4 acc[4] = {};
    if (half == 0) mfma_chain<4>(base, bsrc, acc);
    else           mfma_chain<3>(base, bsrc, acc);

    // --- extract dots: C/D map col=lane&15, row=(lane>>4)*4+reg [m89] ---
    float* lrow = logits[rp];
    if ((lane & 15) == 0) {
        const int rb = (lane >> 4) * 4;
        const int tb = half ? 4 : 0;
        const int nt = half ? 3 : 4;
        #pragma unroll
        for (int t = 0; t < 4; ++t) {
            if (t < nt) {
                floatx4 v = acc[t] * TEMP_INV;
                *(floatx4*)(lrow + (tb + t) * 16 + rb) = v;
            }
        }
    }
    __syncthreads();

    // --- half-0 wave: logsumexp over logits[0..100]; loss = lse - logits[0] ---
    if (half == 0) {
        const float v0 = lrow[lane];
        const float v1 = (lane <= NLOGITS - 65) ? lrow[64 + lane] : -INFINITY;
        float m = fmaxf(v0, v1);
        #pragma unroll
        for (int off = 32; off > 0; off >>= 1) m = fmaxf(m, __shfl_xor(m, off));
        float e = expf(v0 - m);
        if (lane <= NLOGITS - 65) e += expf(v1 - m);
        #pragma unroll
        for (int off = 32; off > 0; off >>= 1) e += __shfl_xor(e, off);
        if (lane == 0) row_loss[i] = (m + logf(e)) - lrow[0];
    }
}

// Kernel 3: deterministic final mean over the 2048 row losses.
__global__ void cl_reduce_kernel(const float* __restrict__ row_loss,
                                 float* __restrict__ out) {
    const int tid = threadIdx.x; // 256
    float s = 0.f;
    for (int i = tid; i < NROWS; i += 256) s += row_loss[i];
    #pragma unroll
    for (int off = 32; off > 0; off >>= 1) s += __shfl_down(s, off);
    __shared__ float sw[4];
    const int wave = tid >> 6, lane = tid & 63;
    if (lane == 0) sw[wave] = s;
    __syncthreads();
    if (tid == 0) out[0] = (sw[0] + sw[1] + sw[2] + sw[3]) / (float)NROWS;
}

extern "C" void kernel_launch(void* const* d_in, const int* in_sizes, int n_in,
                              void* d_out, int out_size, void* d_ws, size_t ws_size,
                              hipStream_t stream) {
    const float* preds   = (const float*)d_in[0];
    const float* targets = (const float*)d_in[1];
    const int*   neg_idx = (const int*)d_in[2];
    float* out = (float*)d_out;

    // workspace: tn_bf16 (3 MB, aligned at base) | row_loss[N]
    __hip_bfloat16* tn = (__hip_bfloat16*)d_ws;
    float* row_loss = (float*)((char*)d_ws + (size_t)NROWS * DDIM * sizeof(__hip_bfloat16));

    cl_prep_kernel<<<NROWS / 4, 256, 0, stream>>>(targets, tn);
    cl_rowloss_kernel<<<NROWS / 2, 256, 0, stream>>>(preds, tn, neg_idx, row_loss);
    cl_reduce_kernel<<<1, 256, 0, stream>>>(row_loss, out);
}

// Round 6
// 37.973 us; speedup vs baseline: 1.3653x; 1.3468x over previous
//
#include <hip/hip_runtime.h>
#include <hip/hip_bf16.h>
#include <math.h>

// Problem constants (fixed by setup_inputs): B=8, M=256, D=768, K=100
#define NROWS 2048
#define DDIM  768
#define KNEG  100
#define NLOGITS 101
#define MT 7             // ceil(101/16) M-tiles -> 112 padded logits
#define KT 24            // 768 / 32 K-steps
#define KW 6             // K-steps per wave (24 / 4 waves)
#define PADROW 776       // 768 + 8 bf16 pad: row stride 1552B = 388 words ≡ 4 mod 32 banks

typedef __attribute__((ext_vector_type(8))) short short8;   // 8 bf16 MFMA frag
typedef __attribute__((ext_vector_type(4))) float floatx4;  // MFMA accumulator

static constexpr float TEMP_INV = 10.0f;   // 1 / 0.1
static constexpr float EPS_NORM = 1e-8f;

__device__ __forceinline__ unsigned pack_bf2(float a, float b) {
    __hip_bfloat16 ha = __float2bfloat16(a), hb = __float2bfloat16(b);
    unsigned short sa, sb;
    __builtin_memcpy(&sa, &ha, 2);
    __builtin_memcpy(&sb, &hb, 2);
    return (unsigned)sa | ((unsigned)sb << 16);
}

// Kernel 1: normalize target rows -> bf16 (3 MB total; L2-resident gather src).
__global__ __launch_bounds__(256) void cl_prep_kernel(
        const float* __restrict__ targets,
        __hip_bfloat16* __restrict__ tn) {
    const int wave = threadIdx.x >> 6, lane = threadIdx.x & 63;
    const int row = blockIdx.x * 4 + wave;
    const float4* tv = (const float4*)(targets + (size_t)row * DDIM);
    const float4 a0 = tv[2 * lane], a1 = tv[2 * lane + 1], b0 = tv[128 + lane];

    float ss = 0.f;
    ss = fmaf(a0.x, a0.x, ss); ss = fmaf(a0.y, a0.y, ss);
    ss = fmaf(a0.z, a0.z, ss); ss = fmaf(a0.w, a0.w, ss);
    ss = fmaf(a1.x, a1.x, ss); ss = fmaf(a1.y, a1.y, ss);
    ss = fmaf(a1.z, a1.z, ss); ss = fmaf(a1.w, a1.w, ss);
    ss = fmaf(b0.x, b0.x, ss); ss = fmaf(b0.y, b0.y, ss);
    ss = fmaf(b0.z, b0.z, ss); ss = fmaf(b0.w, b0.w, ss);
    #pragma unroll
    for (int off = 32; off > 0; off >>= 1) ss += __shfl_xor(ss, off);
    const float it = 1.0f / fmaxf(sqrtf(ss), EPS_NORM);

    uint4 ua;
    ua.x = pack_bf2(a0.x * it, a0.y * it);
    ua.y = pack_bf2(a0.z * it, a0.w * it);
    ua.z = pack_bf2(a1.x * it, a1.y * it);
    ua.w = pack_bf2(a1.z * it, a1.w * it);
    uint2 ub;
    ub.x = pack_bf2(b0.x * it, b0.y * it);
    ub.y = pack_bf2(b0.z * it, b0.w * it);

    __hip_bfloat16* trow = tn + (size_t)row * DDIM;
    ((uint4*)trow)[lane] = ua;          // dims [8*lane, 8*lane+8)
    ((uint2*)(trow + 512))[lane] = ub;  // dims [512+4*lane, +4)
}

// Kernel 2: one block (4 waves) per pred row. Gathered target rows staged
// whole-row COALESCED into LDS (double-buffered 16-row tiles); MFMA A-frags
// read from LDS; 4 waves k-partition (6 K-steps each); partial dots combined
// via LDS; wave 0 does the logsumexp.
__global__ __launch_bounds__(256, 3) void cl_rowloss_kernel(
        const float* __restrict__ preds,
        const __hip_bfloat16* __restrict__ tn,
        const int* __restrict__ neg_idx,
        float* __restrict__ row_loss) {
    const int i = blockIdx.x;
    const int tid = threadIdx.x;
    const int wave = tid >> 6, lane = tid & 63;

    __shared__ __align__(16) unsigned short pn[DDIM];            // pred, bf16
    __shared__ __align__(16) unsigned short Ab[2][16 * PADROW];  // staged tiles
    __shared__ __align__(16) float parts[4][MT * 16];            // per-wave partial dots
    __shared__ int idx_lds[MT * 16];

    // --- gather row indices for all 112 padded logits ---
    if (tid < MT * 16) {
        const int j = tid;
        idx_lds[j] = (j == 0 || j > KNEG) ? i : neg_idx[(size_t)i * KNEG + j - 1];
    }
    __syncthreads();

    // --- prologue: wave 0 normalizes pred -> pn; waves 1-3 stage tile 0 ---
    if (wave == 0) {
        const float4* pv = (const float4*)(preds + (size_t)i * DDIM);
        const float4 a0 = pv[2 * lane], a1 = pv[2 * lane + 1], b0 = pv[128 + lane];
        float ss = 0.f;
        ss = fmaf(a0.x, a0.x, ss); ss = fmaf(a0.y, a0.y, ss);
        ss = fmaf(a0.z, a0.z, ss); ss = fmaf(a0.w, a0.w, ss);
        ss = fmaf(a1.x, a1.x, ss); ss = fmaf(a1.y, a1.y, ss);
        ss = fmaf(a1.z, a1.z, ss); ss = fmaf(a1.w, a1.w, ss);
        ss = fmaf(b0.x, b0.x, ss); ss = fmaf(b0.y, b0.y, ss);
        ss = fmaf(b0.z, b0.z, ss); ss = fmaf(b0.w, b0.w, ss);
        #pragma unroll
        for (int off = 32; off > 0; off >>= 1) ss += __shfl_xor(ss, off);
        const float inv = 1.0f / fmaxf(sqrtf(ss), EPS_NORM);
        uint4 ua;
        ua.x = pack_bf2(a0.x * inv, a0.y * inv);
        ua.y = pack_bf2(a0.z * inv, a0.w * inv);
        ua.z = pack_bf2(a1.x * inv, a1.y * inv);
        ua.w = pack_bf2(a1.z * inv, a1.w * inv);
        uint2 ub;
        ub.x = pack_bf2(b0.x * inv, b0.y * inv);
        ub.y = pack_bf2(b0.z * inv, b0.w * inv);
        ((uint4*)pn)[lane] = ua;
        ((uint2*)(pn + 512))[lane] = ub;
    } else {
        // stage tile 0: 16 rows x 1536B = 1536 chunks of 16B, 192 threads x 8
        #pragma unroll
        for (int it = 0; it < 8; ++it) {
            const int g = (tid - 64) + 192 * it;       // 0..1535
            const int r = g / 96, c = g - r * 96;      // row-in-tile, 16B chunk
            const uint4 v = ((const uint4*)(tn + (size_t)idx_lds[r] * DDIM))[c];
            *(uint4*)(&Ab[0][r * PADROW + c * 8]) = v;
        }
    }
    __syncthreads();

    // --- main loop over 7 M-tiles, double-buffered staging ---
    floatx4 acc[MT] = {};
    const int kbase = wave * KW;

    for (int t = 0; t < MT; ++t) {
        const int cur = t & 1;
        // (a) issue next tile's coalesced gather loads (T14 issue-early)
        uint4 stg[6]; int dst[6];
        if (t < MT - 1) {
            #pragma unroll
            for (int it = 0; it < 6; ++it) {
                const int g = tid + 256 * it;          // 0..1535
                const int r = g / 96, c = g - r * 96;
                stg[it] = ((const uint4*)(tn + (size_t)idx_lds[(t + 1) * 16 + r] * DDIM))[c];
                dst[it] = r * PADROW + c * 8;
            }
        }
        // (b) compute tile t: this wave's 6 K-steps
        #pragma unroll
        for (int kk = 0; kk < KW; ++kk) {
            const int k = kbase + kk;
            const short8 bf = *(const short8*)(&pn[k * 32 + (lane >> 4) * 8]);
            const short8 af = *(const short8*)(
                &Ab[cur][(lane & 15) * PADROW + k * 32 + (lane >> 4) * 8]);
            acc[t] = __builtin_amdgcn_mfma_f32_16x16x32_bf16(af, bf, acc[t], 0, 0, 0);
        }
        // (c) write staged data (vmcnt drains here, after compute)
        if (t < MT - 1) {
            #pragma unroll
            for (int it = 0; it < 6; ++it)
                *(uint4*)(&Ab[cur ^ 1][dst[it]]) = stg[it];
        }
        __syncthreads();
    }

    // --- per-wave partial dots -> LDS. C/D map: col=lane&15, row=(lane>>4)*4+reg ---
    if ((lane & 15) == 0) {
        const int rb = (lane >> 4) * 4;
        #pragma unroll
        for (int t = 0; t < MT; ++t)
            *(floatx4*)(&parts[wave][t * 16 + rb]) = acc[t];
    }
    __syncthreads();

    // --- wave 0: combine 4 k-partials, logsumexp over logits[0..100] ---
    if (wave == 0) {
        const float v0 = (parts[0][lane] + parts[1][lane] +
                          parts[2][lane] + parts[3][lane]) * TEMP_INV;
        float v1 = -INFINITY;
        if (lane <= NLOGITS - 65)
            v1 = (parts[0][64 + lane] + parts[1][64 + lane] +
                  parts[2][64 + lane] + parts[3][64 + lane]) * TEMP_INV;
        const float l0 = __shfl(v0, 0);
        float m = fmaxf(v0, v1);
        #pragma unroll
        for (int off = 32; off > 0; off >>= 1) m = fmaxf(m, __shfl_xor(m, off));
        float e = expf(v0 - m);
        if (lane <= NLOGITS - 65) e += expf(v1 - m);
        #pragma unroll
        for (int off = 32; off > 0; off >>= 1) e += __shfl_xor(e, off);
        if (lane == 0) row_loss[i] = (m + logf(e)) - l0;
    }
}

// Kernel 3: deterministic final mean over the 2048 row losses.
__global__ void cl_reduce_kernel(const float* __restrict__ row_loss,
                                 float* __restrict__ out) {
    const int tid = threadIdx.x; // 256
    float s = 0.f;
    for (int i = tid; i < NROWS; i += 256) s += row_loss[i];
    #pragma unroll
    for (int off = 32; off > 0; off >>= 1) s += __shfl_down(s, off);
    __shared__ float sw[4];
    const int wave = tid >> 6, lane = tid & 63;
    if (lane == 0) sw[wave] = s;
    __syncthreads();
    if (tid == 0) out[0] = (sw[0] + sw[1] + sw[2] + sw[3]) / (float)NROWS;
}

extern "C" void kernel_launch(void* const* d_in, const int* in_sizes, int n_in,
                              void* d_out, int out_size, void* d_ws, size_t ws_size,
                              hipStream_t stream) {
    const float* preds   = (const float*)d_in[0];
    const float* targets = (const float*)d_in[1];
    const int*   neg_idx = (const int*)d_in[2];
    float* out = (float*)d_out;

    // workspace: tn_bf16 (3 MB, aligned at base) | row_loss[N]
    __hip_bfloat16* tn = (__hip_bfloat16*)d_ws;
    float* row_loss = (float*)((char*)d_ws + (size_t)NROWS * DDIM * sizeof(__hip_bfloat16));

    cl_prep_kernel<<<NROWS / 4, 256, 0, stream>>>(targets, tn);
    cl_rowloss_kernel<<<NROWS, 256, 0, stream>>>(preds, tn, neg_idx, row_loss);
    cl_reduce_kernel<<<1, 256, 0, stream>>>(row_loss, out);
}

// Round 7
// 25.919 us; speedup vs baseline: 2.0002x; 1.4651x over previous
//
#include <hip/hip_runtime.h>
#include <hip/hip_bf16.h>
#include <math.h>

// Problem constants (fixed by setup_inputs): B=8, M=256, D=768, K=100
#define NROWS 2048
#define DDIM  768
#define KNEG  100
#define NLOGITS 101
#define MT 7             // ceil(101/16) M-tiles -> 112 padded logits
#define KW 6             // K-steps per wave (24 / 4 waves)
#define ROWB 784         // 768 fp8 + 16B pad: 196 words/row ≡ 4 mod 32 banks

typedef __attribute__((ext_vector_type(4))) float floatx4;  // MFMA accumulator

static constexpr float TEMP_INV = 10.0f;   // 1 / 0.1
static constexpr float EPS_NORM = 1e-8f;

// pack 4 floats -> 4 fp8 e4m3 (OCP on gfx950) in a uint
__device__ __forceinline__ unsigned pack_fp8x4(float a, float b, float c, float d) {
    int u = 0;
    u = __builtin_amdgcn_cvt_pk_fp8_f32(a, b, u, false);
    u = __builtin_amdgcn_cvt_pk_fp8_f32(c, d, u, true);
    return (unsigned)u;
}

// Kernel 1: normalize target rows -> fp8 (1.5 MB total; L2-resident gather src).
// One wave per row; LDS bounce to coalesce the 12B/lane layout into uint4 stores.
__global__ __launch_bounds__(256) void cl_prep_kernel(
        const float* __restrict__ targets,
        unsigned char* __restrict__ tn8) {
    const int wave = threadIdx.x >> 6, lane = threadIdx.x & 63;
    const int row = blockIdx.x * 4 + wave;
    const float4* tv = (const float4*)(targets + (size_t)row * DDIM);
    // dims: a0,a1 = [8*lane, 8*lane+8); b0 = [512+4*lane, +4)
    const float4 a0 = tv[2 * lane], a1 = tv[2 * lane + 1], b0 = tv[128 + lane];

    float ss = 0.f;
    ss = fmaf(a0.x, a0.x, ss); ss = fmaf(a0.y, a0.y, ss);
    ss = fmaf(a0.z, a0.z, ss); ss = fmaf(a0.w, a0.w, ss);
    ss = fmaf(a1.x, a1.x, ss); ss = fmaf(a1.y, a1.y, ss);
    ss = fmaf(a1.z, a1.z, ss); ss = fmaf(a1.w, a1.w, ss);
    ss = fmaf(b0.x, b0.x, ss); ss = fmaf(b0.y, b0.y, ss);
    ss = fmaf(b0.z, b0.z, ss); ss = fmaf(b0.w, b0.w, ss);
    #pragma unroll
    for (int off = 32; off > 0; off >>= 1) ss += __shfl_xor(ss, off);
    const float it = 1.0f / fmaxf(sqrtf(ss), EPS_NORM);

    const unsigned u0 = pack_fp8x4(a0.x * it, a0.y * it, a0.z * it, a0.w * it);
    const unsigned u1 = pack_fp8x4(a1.x * it, a1.y * it, a1.z * it, a1.w * it);
    const unsigned u2 = pack_fp8x4(b0.x * it, b0.y * it, b0.z * it, b0.w * it);

    __shared__ __align__(16) unsigned char buf[4][DDIM];
    *(uint2*)(&buf[wave][8 * lane]) = make_uint2(u0, u1);
    *(unsigned*)(&buf[wave][512 + 4 * lane]) = u2;
    __syncthreads();
    if (lane < 48)
        ((uint4*)(tn8 + (size_t)row * DDIM))[lane] = *(const uint4*)(&buf[wave][16 * lane]);
}

// Kernel 2: one block (4 waves) per pred row. Gathered target rows staged
// whole-row COALESCED into LDS as fp8 (double-buffered 16-row tiles, padded);
// fp8 MFMA A-frags from LDS, B-frags (pred) hoisted in registers; 4 waves
// k-partition; partials combined via LDS; wave 0 logsumexp.
__global__ __launch_bounds__(256, 4) void cl_rowloss_kernel(
        const float* __restrict__ preds,
        const unsigned char* __restrict__ tn8,
        const int* __restrict__ neg_idx,
        float* __restrict__ row_loss) {
    const int i = blockIdx.x;
    const int tid = threadIdx.x;
    const int wave = tid >> 6, lane = tid & 63;

    __shared__ __align__(16) unsigned char pn8[DDIM];          // pred, fp8
    __shared__ __align__(16) unsigned char Ab[2][16 * ROWB];   // staged tiles (24.5KB)
    __shared__ __align__(16) float parts[4][MT * 16];          // per-wave partial dots
    __shared__ int idx_lds[MT * 16];

    // --- gather row indices for all 112 padded logits ---
    if (tid < MT * 16)
        idx_lds[tid] = (tid == 0 || tid > KNEG) ? i : neg_idx[(size_t)i * KNEG + tid - 1];
    __syncthreads();

    // --- prologue: wave 0 normalizes pred -> pn8; waves 1-3 stage tile 0 ---
    if (wave == 0) {
        const float4* pv = (const float4*)(preds + (size_t)i * DDIM);
        const float4 a0 = pv[2 * lane], a1 = pv[2 * lane + 1], b0 = pv[128 + lane];
        float ss = 0.f;
        ss = fmaf(a0.x, a0.x, ss); ss = fmaf(a0.y, a0.y, ss);
        ss = fmaf(a0.z, a0.z, ss); ss = fmaf(a0.w, a0.w, ss);
        ss = fmaf(a1.x, a1.x, ss); ss = fmaf(a1.y, a1.y, ss);
        ss = fmaf(a1.z, a1.z, ss); ss = fmaf(a1.w, a1.w, ss);
        ss = fmaf(b0.x, b0.x, ss); ss = fmaf(b0.y, b0.y, ss);
        ss = fmaf(b0.z, b0.z, ss); ss = fmaf(b0.w, b0.w, ss);
        #pragma unroll
        for (int off = 32; off > 0; off >>= 1) ss += __shfl_xor(ss, off);
        const float inv = 1.0f / fmaxf(sqrtf(ss), EPS_NORM);
        *(uint2*)(&pn8[8 * lane]) = make_uint2(
            pack_fp8x4(a0.x * inv, a0.y * inv, a0.z * inv, a0.w * inv),
            pack_fp8x4(a1.x * inv, a1.y * inv, a1.z * inv, a1.w * inv));
        *(unsigned*)(&pn8[512 + 4 * lane]) =
            pack_fp8x4(b0.x * inv, b0.y * inv, b0.z * inv, b0.w * inv);
    } else {
        // stage tile 0: 16 rows x 768B = 768 chunks of 16B, 192 threads x 4
        #pragma unroll
        for (int it = 0; it < 4; ++it) {
            const int g = (tid - 64) + 192 * it;       // 0..767
            const int r = g / 48, c = g - r * 48;      // row-in-tile, 16B chunk
            const uint4 v = ((const uint4*)(tn8 + (size_t)idx_lds[r] * DDIM))[c];
            *(uint4*)(&Ab[0][r * ROWB + c * 16]) = v;
        }
    }
    __syncthreads();

    // --- B-frags (pred) hoisted to registers: 6 x 8 fp8 per wave ---
    const int kb = wave * KW;
    long long bfr[KW];
    #pragma unroll
    for (int kk = 0; kk < KW; ++kk)
        bfr[kk] = *(const long long*)(&pn8[(kb + kk) * 32 + (lane >> 4) * 8]);

    const int abase = (lane & 15) * ROWB + kb * 32 + (lane >> 4) * 8;

    // --- main loop over 7 M-tiles, double-buffered staging ---
    floatx4 acc[MT] = {};
    #pragma unroll
    for (int t = 0; t < MT; ++t) {
        const int cur = t & 1;
        // (a) issue next tile's coalesced gather loads (issue-early)
        uint4 stg[3]; int dst[3];
        if (t < MT - 1) {
            #pragma unroll
            for (int it = 0; it < 3; ++it) {
                const int g = tid + 256 * it;          // 0..767
                const int r = g / 48, c = g - r * 48;
                stg[it] = ((const uint4*)(tn8 + (size_t)idx_lds[(t + 1) * 16 + r] * DDIM))[c];
                dst[it] = r * ROWB + c * 16;
            }
        }
        // (b) compute tile t: this wave's 6 K-steps (fp8 MFMA, b64 A-frags)
        #pragma unroll
        for (int kk = 0; kk < KW; ++kk) {
            const long long af = *(const long long*)(&Ab[cur][abase + kk * 32]);
            acc[t] = __builtin_amdgcn_mfma_f32_16x16x32_fp8_fp8(af, bfr[kk],
                                                                acc[t], 0, 0, 0);
        }
        // (c) write staged data (vmcnt drains here, after compute)
        if (t < MT - 1) {
            #pragma unroll
            for (int it = 0; it < 3; ++it)
                *(uint4*)(&Ab[cur ^ 1][dst[it]]) = stg[it];
        }
        __syncthreads();
    }

    // --- per-wave partial dots -> LDS. C/D map: col=lane&15, row=(lane>>4)*4+reg ---
    if ((lane & 15) == 0) {
        const int rb = (lane >> 4) * 4;
        #pragma unroll
        for (int t = 0; t < MT; ++t)
            *(floatx4*)(&parts[wave][t * 16 + rb]) = acc[t];
    }
    __syncthreads();

    // --- wave 0: combine 4 k-partials, logsumexp over logits[0..100] ---
    if (wave == 0) {
        const float v0 = (parts[0][lane] + parts[1][lane] +
                          parts[2][lane] + parts[3][lane]) * TEMP_INV;
        float v1 = -INFINITY;
        if (lane <= NLOGITS - 65)
            v1 = (parts[0][64 + lane] + parts[1][64 + lane] +
                  parts[2][64 + lane] + parts[3][64 + lane]) * TEMP_INV;
        const float l0 = __shfl(v0, 0);
        float m = fmaxf(v0, v1);
        #pragma unroll
        for (int off = 32; off > 0; off >>= 1) m = fmaxf(m, __shfl_xor(m, off));
        float e = expf(v0 - m);
        if (lane <= NLOGITS - 65) e += expf(v1 - m);
        #pragma unroll
        for (int off = 32; off > 0; off >>= 1) e += __shfl_xor(e, off);
        if (lane == 0) row_loss[i] = (m + logf(e)) - l0;
    }
}

// Kernel 3: deterministic final mean over the 2048 row losses.
__global__ void cl_reduce_kernel(const float* __restrict__ row_loss,
                                 float* __restrict__ out) {
    const int tid = threadIdx.x; // 256
    float s = 0.f;
    #pragma unroll
    for (int c = 0; c < 2; ++c) {
        const float4 v = ((const float4*)row_loss)[tid + 256 * c];
        s += (v.x + v.y) + (v.z + v.w);
    }
    #pragma unroll
    for (int off = 32; off > 0; off >>= 1) s += __shfl_down(s, off);
    __shared__ float sw[4];
    const int wave = tid >> 6, lane = tid & 63;
    if (lane == 0) sw[wave] = s;
    __syncthreads();
    if (tid == 0) out[0] = (sw[0] + sw[1] + sw[2] + sw[3]) / (float)NROWS;
}

extern "C" void kernel_launch(void* const* d_in, const int* in_sizes, int n_in,
                              void* d_out, int out_size, void* d_ws, size_t ws_size,
                              hipStream_t stream) {
    const float* preds   = (const float*)d_in[0];
    const float* targets = (const float*)d_in[1];
    const int*   neg_idx = (const int*)d_in[2];
    float* out = (float*)d_out;

    // workspace: tn8 (1.5 MB, aligned at base) | row_loss[N]
    unsigned char* tn8 = (unsigned char*)d_ws;
    float* row_loss = (float*)((char*)d_ws + (size_t)NROWS * DDIM);

    cl_prep_kernel<<<NROWS / 4, 256, 0, stream>>>(targets, tn8);
    cl_rowloss_kernel<<<NROWS, 256, 0, stream>>>(preds, tn8, neg_idx, row_loss);
    cl_reduce_kernel<<<1, 256, 0, stream>>>(row_loss, out);
}